// Round 12
// baseline (236.538 us; speedup 1.0000x reference)
//
#include <hip/hip_runtime.h>

#define B_ 2
#define S_ 2048
#define D_ 2048
#define H_ 16
#define HD_ 128

typedef _Float16 fp16x2 __attribute__((ext_vector_type(2)));
typedef _Float16 fp16x4 __attribute__((ext_vector_type(4)));
typedef _Float16 fp16x8 __attribute__((ext_vector_type(8)));
typedef float f32x4 __attribute__((ext_vector_type(4)));

__device__ __forceinline__ void gl_lds16(const _Float16* g, _Float16* l) {
  __builtin_amdgcn_global_load_lds((const __attribute__((address_space(1))) void*)g,
                                   (__attribute__((address_space(3))) void*)l, 16, 0, 0);
}

// ---------------- cast x fp32 -> fp16 ----------------
__global__ __launch_bounds__(256) void k_cast(const float* __restrict__ in,
                                              _Float16* __restrict__ out, int n4) {
  int i = blockIdx.x * 256 + threadIdx.x;
  if (i >= n4) return;
  f32x4 v = ((const f32x4*)in)[i];
  fp16x4 h = {(_Float16)v[0], (_Float16)v[1], (_Float16)v[2], (_Float16)v[3]};
  ((fp16x4*)out)[i] = h;
}

// ---------------- transpose+cast 4x W[2048][2048] fp32 -> WT[n][k] fp16 ----------------
__global__ __launch_bounds__(256) void k_trw4(const float* __restrict__ w0,
                                              const float* __restrict__ w1,
                                              const float* __restrict__ w2,
                                              const float* __restrict__ w3,
                                              _Float16* __restrict__ o0,
                                              _Float16* __restrict__ o1,
                                              _Float16* __restrict__ o2,
                                              _Float16* __restrict__ o3) {
  __shared__ float tile[64][65];
  const float* w = (blockIdx.z == 0) ? w0 : (blockIdx.z == 1) ? w1 : (blockIdx.z == 2) ? w2 : w3;
  _Float16* wt = (blockIdx.z == 0) ? o0 : (blockIdx.z == 1) ? o1 : (blockIdx.z == 2) ? o2 : o3;
  int k0 = blockIdx.y * 64, n0 = blockIdx.x * 64;
  int t = threadIdx.x;
  int r = t >> 2, c0 = (t & 3) * 16;
  const float* ip = w + (size_t)(k0 + r) * D_ + n0 + c0;
#pragma unroll
  for (int j = 0; j < 16; j += 4) {
    f32x4 v = *(const f32x4*)(ip + j);
    tile[r][c0 + j] = v[0]; tile[r][c0 + j + 1] = v[1];
    tile[r][c0 + j + 2] = v[2]; tile[r][c0 + j + 3] = v[3];
  }
  __syncthreads();
  _Float16* op = wt + (size_t)(n0 + r) * D_ + k0 + c0;
#pragma unroll
  for (int j = 0; j < 16; j += 8) {
    fp16x8 v;
#pragma unroll
    for (int q = 0; q < 8; ++q) v[q] = (_Float16)tile[c0 + j + q][r];
    *(fp16x8*)(op + j) = v;
  }
}

// ---------------- QKV GEMM, 256x256 tile, 4-phase fine interleave ----------------
// C[4096][6144] = A16[4096][2048] * (BTqkv[6144][2048])^T, never materialized:
//   n in [0,2048) -> rope -> Qo; [2048,4096) -> rope -> Ko; [4096,6144) -> Vo blocked.
// 512 threads = 8 waves (2M x 4N), per-wave 128x64 output (acc 8x4).
// LDS 128KB: A [2buf][4u][64][64] halfs @0, B same @32768. XOR swizzle via
// pre-swizzled global source (slot lc^lr); reads XOR (row&7)*8 halfs.
// Per K-tile, 4 phases (m201 structure): phase p =
//   { ds_read: B all (p0 only, 8) + A m{2p,2p+1} (4)  |  gl_lds: t+1 A (p0) / B (p1)
//     -> [p3: vmcnt(0), loads 2+ phases old] -> barrier -> lgkmcnt(0)+sched_barrier(0)
//     -> setprio(1) 16 MFMA setprio(0) -> barrier }
// B-frags register-cached across the tile. Fine phasing wave-staggers LDS vs MFMA pipes.
__global__ __launch_bounds__(512) void k_qkv256(const _Float16* __restrict__ A,
                                                const _Float16* __restrict__ BT,
                                                const float* __restrict__ cosT,
                                                const float* __restrict__ sinT,
                                                _Float16* __restrict__ Qo,
                                                _Float16* __restrict__ Ko,
                                                _Float16* __restrict__ Vo) {
  __shared__ __align__(16) _Float16 smem[65536];  // 128 KiB
  const int tid = threadIdx.x;
  const int w = tid >> 6, lane = tid & 63;
  const int l15 = lane & 15, lg = lane >> 4;
  // XCD map: 24 n-tiles x 16 m-tiles; XCD x owns n-tiles [3x,3x+3) x all m
  const int bid = blockIdx.x;
  const int xcd = bid & 7, j = bid >> 3;  // j in [0,48)
  const int m0 = (j / 3) * 256;
  const int n0 = (xcd * 3 + j % 3) * 256;
  const int wm = (w >> 2) * 128;  // 2 M-groups
  const int wn = (w & 3) * 64;    // 4 N-groups
  // staging: wave w covers rows [w*8,w*8+8) of each 64-row unit; slot lc (16B)
  const int lr = lane >> 3, lc = lane & 7;
  const int scol = (lc ^ lr) << 3;  // pre-swizzled source col (halfs)
  const _Float16* Asrc = A + (size_t)(m0 + w * 8 + lr) * 2048 + scol;
  const _Float16* Bsrc = BT + (size_t)(n0 + w * 8 + lr) * 2048 + scol;
  _Float16* dstA = smem + w * 512;
  _Float16* dstB = smem + 32768 + w * 512;

  auto stageA = [&](int stg, int u, int k0) {
    gl_lds16(Asrc + (size_t)u * 64 * 2048 + k0, dstA + stg * 16384 + u * 4096);
  };
  auto stageB = [&](int stg, int u, int k0) {
    gl_lds16(Bsrc + (size_t)u * 64 * 2048 + k0, dstB + stg * 16384 + u * 4096);
  };

  // fragment LDS offsets (halfs), constant per thread
  int aoff[8], boff[4];
#pragma unroll
  for (int mi = 0; mi < 8; ++mi) {
    const int r = wm + mi * 16 + l15;  // [0,256)
    aoff[mi] = (r >> 6) * 4096 + (r & 63) * 64;
  }
#pragma unroll
  for (int ni = 0; ni < 4; ++ni) {
    const int r = wn + ni * 16 + l15;  // [0,256)
    boff[ni] = (r >> 6) * 4096 + (r & 63) * 64;
  }
  const int swz[2] = {(lg * 8) ^ ((l15 & 7) * 8), (32 + lg * 8) ^ ((l15 & 7) * 8)};

  f32x4 acc[8][4] = {};

  // prologue: tile 0 -> buf 0, drain, sync
#pragma unroll
  for (int u = 0; u < 4; ++u) stageA(0, u, 0);
#pragma unroll
  for (int u = 0; u < 4; ++u) stageB(0, u, 0);
  asm volatile("s_waitcnt vmcnt(0)" ::: "memory");
  __builtin_amdgcn_s_barrier();

  for (int t = 0; t < 32; ++t) {
    const int cur = t & 1, nxt = cur ^ 1;
    const bool pf = (t + 1) < 32;
    const int k1 = (t + 1) * 64;
    const _Float16* sA = smem + cur * 16384;
    const _Float16* sB = smem + 32768 + cur * 16384;
    fp16x8 bf[4][2];
#pragma unroll
    for (int p = 0; p < 4; ++p) {
      if (p == 0) {
#pragma unroll
        for (int ni = 0; ni < 4; ++ni)
#pragma unroll
          for (int ks = 0; ks < 2; ++ks)
            bf[ni][ks] = *(const fp16x8*)(sB + boff[ni] + swz[ks]);
      }
      fp16x8 af[2][2];
#pragma unroll
      for (int q = 0; q < 2; ++q)
#pragma unroll
        for (int ks = 0; ks < 2; ++ks)
          af[q][ks] = *(const fp16x8*)(sA + aoff[2 * p + q] + swz[ks]);
      if (pf) {
        if (p == 0) {
          stageA(nxt, 0, k1); stageA(nxt, 1, k1); stageA(nxt, 2, k1); stageA(nxt, 3, k1);
        } else if (p == 1) {
          stageB(nxt, 0, k1); stageB(nxt, 1, k1); stageB(nxt, 2, k1); stageB(nxt, 3, k1);
        }
      }
      // tile-boundary drain folded into phase-3's start barrier: loads 2+ phases old
      if (p == 3) asm volatile("s_waitcnt vmcnt(0)" ::: "memory");
      __builtin_amdgcn_s_barrier();
      asm volatile("s_waitcnt lgkmcnt(0)" ::: "memory");
      __builtin_amdgcn_sched_barrier(0);
      __builtin_amdgcn_s_setprio(1);
#pragma unroll
      for (int q = 0; q < 2; ++q)
#pragma unroll
        for (int ni = 0; ni < 4; ++ni)
#pragma unroll
          for (int ks = 0; ks < 2; ++ks)
            acc[2 * p + q][ni] = __builtin_amdgcn_mfma_f32_16x16x32_f16(
                af[q][ks], bf[ni][ks], acc[2 * p + q][ni], 0, 0, 0);
      __builtin_amdgcn_s_setprio(0);
      __builtin_amdgcn_s_barrier();
    }
  }

  const int region = n0 >> 11;  // 0=Q, 1=K, 2=V (256-tile never crosses regions)
  if (region < 2) {
    _Float16* Out = (region == 0) ? Qo : Ko;
#pragma unroll
    for (int mi = 0; mi < 8; ++mi)
#pragma unroll
      for (int ni = 0; ni < 4; ++ni) {
        const int col = n0 + wn + 16 * ni + l15;
        const int d = col & 127;
        const int h = (col >> 7) & 15;
        const int dp = d >> 1;
        const bool odd = d & 1;
#pragma unroll
        for (int i = 0; i < 4; ++i) {
          const int row = m0 + wm + 16 * mi + 4 * lg + i;
          const int b = row >> 11, sl = row & 2047;
          const float self = acc[mi][ni][i];
          const float partner = __shfl_xor(self, 1);
          const float c = cosT[sl * 64 + dp], sn = sinT[sl * 64 + dp];
          const float val = odd ? (partner * sn + self * c) : (self * c - partner * sn);
          Out[(((size_t)b * H_ + h) * S_ + sl) * HD_ + d] = (_Float16)val;
        }
      }
  } else {
#pragma unroll
    for (int mi = 0; mi < 8; ++mi)
#pragma unroll
      for (int ni = 0; ni < 4; ++ni) {
        const int col = n0 + wn + 16 * ni + l15;
        const int d = col & 127;
        const int h = (col >> 7) & 15;
        const int row0 = m0 + wm + 16 * mi + 4 * lg;
        const int b = row0 >> 11, sl0 = row0 & 2047;
        const int kb = sl0 >> 4, kin = sl0 & 15;
        fp16x4 v4;
#pragma unroll
        for (int i = 0; i < 4; ++i) v4[i] = (_Float16)acc[mi][ni][i];
        *(fp16x4*)(Vo + ((((size_t)b * H_ + h) * 128 + kb) * 128 + d) * 16 + kin) = v4;
      }
  }
}

// ---------------- 256x128-tile GEMM (round-10 schedule), fp32 out (wo) ----------------
__global__ __launch_bounds__(512) void k_gemm_wo(const _Float16* __restrict__ A,
                                                 const _Float16* __restrict__ BT,
                                                 float* __restrict__ Cf) {
  __shared__ __align__(16) _Float16 smem[73728];  // 144 KiB
  const int tid = threadIdx.x;
  const int w = tid >> 6, lane = tid & 63;
  const int l15 = lane & 15, lg = lane >> 4;
  const int NPX = 2;  // n-tiles per XCD (16 total)
  const int bid = blockIdx.x;
  const int xcd = bid & 7, j = bid >> 3;
  const int m0 = (j / NPX) * 256;
  const int n0 = (xcd * NPX + j % NPX) * 128;
  const int wm = (w >> 1) * 64;
  const int wn = (w & 1) * 64;
  const int lr = lane >> 3, lc = lane & 7;
  const int scol = (lc ^ lr) << 3;
  const _Float16* Asrc = A + (size_t)(m0 + w * 8 + lr) * 2048 + scol;
  const _Float16* Bsrc = BT + (size_t)(n0 + w * 8 + lr) * 2048 + scol;
  _Float16* dstA = smem + w * 512;
  _Float16* dstB = smem + 49152 + w * 512;

  auto stageA = [&](int stg, int u, int k0) {
    gl_lds16(Asrc + (size_t)u * 64 * 2048 + k0, dstA + stg * 16384 + u * 4096);
  };
  auto stageB = [&](int stg, int u, int k0) {
    gl_lds16(Bsrc + (size_t)u * 64 * 2048 + k0, dstB + stg * 8192 + u * 4096);
  };

  int aoff[4], boff[4];
#pragma unroll
  for (int mi = 0; mi < 4; ++mi) {
    const int row = wm + mi * 16 + l15;
    aoff[mi] = (row >> 6) * 4096 + (row & 63) * 64;
  }
#pragma unroll
  for (int ni = 0; ni < 4; ++ni) {
    const int row = wn + ni * 16 + l15;
    boff[ni] = (row >> 6) * 4096 + (row & 63) * 64;
  }
  const int swz[2] = {(lg * 8) ^ ((l15 & 7) * 8), (32 + lg * 8) ^ ((l15 & 7) * 8)};

  f32x4 acc[4][4] = {};

#pragma unroll
  for (int u = 0; u < 4; ++u) stageA(0, u, 0);
  stageB(0, 0, 0); stageB(0, 1, 0);
#pragma unroll
  for (int u = 0; u < 4; ++u) stageA(1, u, 64);
  stageB(1, 0, 64); stageB(1, 1, 64);
  asm volatile("s_waitcnt vmcnt(6)" ::: "memory");
  __builtin_amdgcn_s_barrier();

  for (int t = 0; t < 32; ++t) {
    const int cur = t % 3;
    const bool pf = (t + 2) < 32;
    const int spf = (t + 2) % 3, kpf = (t + 2) * 64;
    const _Float16* sA = smem + cur * 16384;
    const _Float16* sB = smem + 49152 + cur * 8192;
#pragma unroll
    for (int ks = 0; ks < 2; ++ks) {
      fp16x8 af[4], bf[4];
#pragma unroll
      for (int mi = 0; mi < 4; ++mi) af[mi] = *(const fp16x8*)(sA + aoff[mi] + swz[ks]);
#pragma unroll
      for (int ni = 0; ni < 4; ++ni) bf[ni] = *(const fp16x8*)(sB + boff[ni] + swz[ks]);
      if (ks == 0) {
        if (pf) { stageA(spf, 0, kpf); stageA(spf, 1, kpf); stageA(spf, 2, kpf); }
      } else {
        if (pf) {
          stageA(spf, 3, kpf); stageB(spf, 0, kpf); stageB(spf, 1, kpf);
          asm volatile("s_waitcnt vmcnt(6)" ::: "memory");
        } else {
          asm volatile("s_waitcnt vmcnt(0)" ::: "memory");
        }
      }
      __builtin_amdgcn_s_barrier();
      __builtin_amdgcn_s_setprio(1);
#pragma unroll
      for (int mi = 0; mi < 4; ++mi)
#pragma unroll
        for (int ni = 0; ni < 4; ++ni)
          acc[mi][ni] = __builtin_amdgcn_mfma_f32_16x16x32_f16(af[mi], bf[ni],
                                                               acc[mi][ni], 0, 0, 0);
      __builtin_amdgcn_s_setprio(0);
      __builtin_amdgcn_s_barrier();
    }
  }

#pragma unroll
  for (int mi = 0; mi < 4; ++mi)
#pragma unroll
    for (int ni = 0; ni < 4; ++ni) {
      const size_t row = m0 + wm + 16 * mi + 4 * lg;
      const size_t col = n0 + wn + 16 * ni + l15;
#pragma unroll
      for (int i = 0; i < 4; ++i)
        Cf[(row + i) * 2048 + col] = acc[mi][ni][i];
    }
}

// ---------------- block-sparse flash attention, paired q-groups ----------------
__global__ __launch_bounds__(256) void k_attn(const _Float16* __restrict__ Q,
                                              const _Float16* __restrict__ K,
                                              const _Float16* __restrict__ Vb,
                                              _Float16* __restrict__ Oa) {
  __shared__ __align__(16) _Float16 sK[2][2][2048];  // [buf][slot][16k x 128d swizzled]
  __shared__ __align__(16) _Float16 sV[2][2][2048];  // [buf][slot][128d x 16k]
  const int p = blockIdx.x;
  const int qgA = 31 - p, qgB = p;
  const int hh = blockIdx.y, b = blockIdx.z;
  const int t = threadIdx.x;
  const int w = t >> 6, lane = t & 63;
  const int l15 = lane & 15, lg = lane >> 4, g4 = lg * 4;
  const size_t bh = (size_t)b * H_ + hh;
  const float scale = 0.08838834764831845f;  // 1/sqrt(128)

  const int qbA = 4 * qgA + w, qbB = 4 * qgB + w;
  const int LA = qgA + 4, LB = qgB + 4;
  const int nchA = (LA + 1) >> 1, nchB = (LB + 1) >> 1;
  const int total = nchA + nchB;

  const _Float16* QpA = Q + (bh * S_ + (size_t)qbA * 16 + l15) * HD_ + lg * 8;
  const _Float16* QpB = Q + (bh * S_ + (size_t)qbB * 16 + l15) * HD_ + lg * 8;
  fp16x8 qfA[4], qfB[4];
#pragma unroll
  for (int dd = 0; dd < 4; ++dd) {
    qfA[dd] = *(const fp16x8*)(QpA + dd * 32);
    qfB[dd] = *(const fp16x8*)(QpB + dd * 32);
  }
  f32x4 o[8] = {};
  float mrun = -3.0e38f, lsum = 0.f;

  const int sr = t >> 4, sc = t & 15;
  const int ksrc_off = sr * 128 + (sc ^ (sr & 7)) * 8;  // halfs
  const _Float16* Kb_g = K + bh * S_ * HD_;
  const _Float16* Vb_g = Vb + bh * (size_t)(128 * 2048);

  auto kbof = [&](int qg, int idx) { return idx < qg ? 4 * idx + 3 : 3 * qg + idx; };
  auto chunk_kbs = [&](int ci, int& kb0, int& kb1) {
    int qg, cil;
    if (ci < nchA) { qg = qgA; cil = ci; } else { qg = qgB; cil = ci - nchA; }
    const int L = qg + 4;
    const int i0 = 2 * cil, i1 = i0 + 1;
    kb0 = kbof(qg, i0);
    kb1 = (i1 < L) ? kbof(qg, i1) : kb0;
  };
  auto stage = [&](int buf, int ci) {
    int kb0, kb1;
    chunk_kbs(ci, kb0, kb1);
    gl_lds16(Kb_g + (size_t)kb0 * 2048 + ksrc_off, &sK[buf][0][w * 512]);
    gl_lds16(Kb_g + (size_t)kb1 * 2048 + ksrc_off, &sK[buf][1][w * 512]);
    gl_lds16(Vb_g + (size_t)kb0 * 2048 + t * 8, &sV[buf][0][w * 512]);
    gl_lds16(Vb_g + (size_t)kb1 * 2048 + t * 8, &sV[buf][1][w * 512]);
  };
  auto flush = [&](int qb) {
    const float inv = 1.f / lsum;
    f32x4 li;
#pragma unroll
    for (int i = 0; i < 4; ++i) li[i] = __shfl(inv, g4 + i);
    _Float16* Op = Oa + ((size_t)b * S_ + (size_t)qb * 16 + g4) * D_ + (size_t)hh * HD_ + l15;
#pragma unroll
    for (int ni = 0; ni < 8; ++ni)
#pragma unroll
      for (int i = 0; i < 4; ++i)
        Op[(size_t)i * D_ + 16 * ni] = (_Float16)(o[ni][i] * li[i]);
  };

  stage(0, 0);

  for (int ci = 0; ci < total; ++ci) {
    const int cur = ci & 1;
    if (ci == nchA) {  // group A complete: write it out, reset state for B
      flush(qbA);
#pragma unroll
      for (int ni = 0; ni < 8; ++ni) o[ni] = f32x4{0.f, 0.f, 0.f, 0.f};
      mrun = -3.0e38f;
      lsum = 0.f;
    }
    if (ci + 1 < total) {
      stage(cur ^ 1, ci + 1);
      asm volatile("s_waitcnt vmcnt(4)" ::: "memory");  // cur chunk arrived, next in flight
    } else {
      asm volatile("s_waitcnt vmcnt(0)" ::: "memory");
    }
    __builtin_amdgcn_s_barrier();

    const bool inA = ci < nchA;
    const int qg = inA ? qgA : qgB;
    const int qb = inA ? qbA : qbB;
    const int cil = inA ? ci : ci - nchA;
    const int L = qg + 4;
    int kb0, kb1;
    chunk_kbs(ci, kb0, kb1);
    const bool v0 = kb0 <= qb;
    const bool v1 = (2 * cil + 1 < L) && (kb1 <= qb);
    f32x4 st[2];
    const float in0 = v0 ? 0.f : -1.0e30f, in1 = v1 ? 0.f : -1.0e30f;
    st[0] = f32x4{in0, in0, in0, in0};
    st[1] = f32x4{in1, in1, in1, in1};

    const char* kl = (const char*)&sK[cur][0][0];
    const int krow = l15 * 256;
#pragma unroll
    for (int dd = 0; dd < 4; ++dd) {
      const int co = ((dd * 4 + lg) ^ (l15 & 7)) * 16;
      fp16x8 k0 = *(const fp16x8*)(kl + krow + co);
      fp16x8 k1 = *(const fp16x8*)(kl + 4096 + krow + co);
      const fp16x8 qf = inA ? qfA[dd] : qfB[dd];
      st[0] = __builtin_amdgcn_mfma_f32_16x16x32_f16(k0, qf, st[0], 0, 0, 0);
      st[1] = __builtin_amdgcn_mfma_f32_16x16x32_f16(k1, qf, st[1], 0, 0, 0);
    }
    float bm = -3.0e38f;
#pragma unroll
    for (int j = 0; j < 2; ++j)
#pragma unroll
      for (int i = 0; i < 4; ++i) {
        st[j][i] *= scale;
        bm = fmaxf(bm, st[j][i]);
      }
    bm = fmaxf(bm, __shfl_xor(bm, 16));
    bm = fmaxf(bm, __shfl_xor(bm, 32));
    const float mnew = fmaxf(mrun, bm);
    const float corr = __expf(mrun - mnew);
    float pr[2][4];
    float ps = 0.f;
#pragma unroll
    for (int j = 0; j < 2; ++j)
#pragma unroll
      for (int i = 0; i < 4; ++i) {
        pr[j][i] = __expf(st[j][i] - mnew);
        ps += pr[j][i];
      }
    ps += __shfl_xor(ps, 16);
    ps += __shfl_xor(ps, 32);
    lsum = lsum * corr + ps;
    mrun = mnew;
    f32x4 c4;
#pragma unroll
    for (int i = 0; i < 4; ++i) c4[i] = __shfl(corr, g4 + i);
#pragma unroll
    for (int ni = 0; ni < 8; ++ni) {
      o[ni][0] *= c4[0]; o[ni][1] *= c4[1]; o[ni][2] *= c4[2]; o[ni][3] *= c4[3];
    }
    fp16x4 ph0 = {(_Float16)pr[0][0], (_Float16)pr[0][1], (_Float16)pr[0][2], (_Float16)pr[0][3]};
    fp16x4 ph1 = {(_Float16)pr[1][0], (_Float16)pr[1][1], (_Float16)pr[1][2], (_Float16)pr[1][3]};
    const char* vl = (const char*)&sV[cur][0][0];
#pragma unroll
    for (int ni = 0; ni < 8; ++ni) {
      const int vo = (16 * ni + l15) * 32 + g4 * 2;
      fp16x4 vv0 = *(const fp16x4*)(vl + vo);
      fp16x4 vv1 = *(const fp16x4*)(vl + 4096 + vo);
      o[ni] = __builtin_amdgcn_mfma_f32_16x16x16f16(ph0, vv0, o[ni], 0, 0, 0);
      o[ni] = __builtin_amdgcn_mfma_f32_16x16x16f16(ph1, vv1, o[ni], 0, 0, 0);
    }
    __builtin_amdgcn_s_barrier();  // all waves done reading buf before it's re-staged
  }

  flush(qbB);
}

extern "C" void kernel_launch(void* const* d_in, const int* in_sizes, int n_in,
                              void* d_out, int out_size, void* d_ws, size_t ws_size,
                              hipStream_t stream) {
  const float* x = (const float*)d_in[0];
  const float* cosT = (const float*)d_in[1];
  const float* sinT = (const float*)d_in[2];
  const float* wq = (const float*)d_in[3];
  const float* wk = (const float*)d_in[4];
  const float* wv = (const float*)d_in[5];
  const float* wo = (const float*)d_in[6];
  float* out = (float*)d_out;
  char* ws = (char*)d_ws;

  _Float16* x16 = (_Float16*)(ws);                    // 16MB, reused as attn out
  _Float16* wtq = (_Float16*)(ws + (16ull << 20));    // 8MB each; wtq/wtk/wtv contiguous = BT[6144][2048]
  _Float16* wtk = (_Float16*)(ws + (24ull << 20));
  _Float16* wtv = (_Float16*)(ws + (32ull << 20));
  _Float16* wto = (_Float16*)(ws + (40ull << 20));
  _Float16* Q16 = (_Float16*)(ws + (48ull << 20));    // 16MB
  _Float16* K16 = (_Float16*)(ws + (64ull << 20));    // 16MB
  _Float16* Vb16 = (_Float16*)(ws + (80ull << 20));   // 16MB (blocked V)

  k_cast<<<8192, 256, 0, stream>>>(x, x16, (B_ * S_ * D_) / 4);
  k_trw4<<<dim3(32, 32, 4), 256, 0, stream>>>(wq, wk, wv, wo, wtq, wtk, wtv, wto);

  k_qkv256<<<384, 512, 0, stream>>>(x16, wtq, cosT, sinT, Q16, K16, Vb16);

  _Float16* attn16 = x16;  // x16 no longer needed after QKV GEMM
  k_attn<<<dim3(16, H_, B_), 256, 0, stream>>>(Q16, K16, Vb16, attn16);

  k_gemm_wo<<<256, 512, 0, stream>>>(attn16, wto, out);
}

// Round 13
// 221.144 us; speedup vs baseline: 1.0696x; 1.0696x over previous
//
#include <hip/hip_runtime.h>

#define B_ 2
#define S_ 2048
#define D_ 2048
#define H_ 16
#define HD_ 128

typedef _Float16 fp16x2 __attribute__((ext_vector_type(2)));
typedef _Float16 fp16x4 __attribute__((ext_vector_type(4)));
typedef _Float16 fp16x8 __attribute__((ext_vector_type(8)));
typedef float f32x4 __attribute__((ext_vector_type(4)));

__device__ __forceinline__ void gl_lds16(const _Float16* g, _Float16* l) {
  __builtin_amdgcn_global_load_lds((const __attribute__((address_space(1))) void*)g,
                                   (__attribute__((address_space(3))) void*)l, 16, 0, 0);
}

// ---------------- cast x fp32 -> fp16 ----------------
__global__ __launch_bounds__(256) void k_cast(const float* __restrict__ in,
                                              _Float16* __restrict__ out, int n4) {
  int i = blockIdx.x * 256 + threadIdx.x;
  if (i >= n4) return;
  f32x4 v = ((const f32x4*)in)[i];
  fp16x4 h = {(_Float16)v[0], (_Float16)v[1], (_Float16)v[2], (_Float16)v[3]};
  ((fp16x4*)out)[i] = h;
}

// ---------------- transpose+cast 4x W[2048][2048] fp32 -> WT[n][k] fp16 ----------------
__global__ __launch_bounds__(256) void k_trw4(const float* __restrict__ w0,
                                              const float* __restrict__ w1,
                                              const float* __restrict__ w2,
                                              const float* __restrict__ w3,
                                              _Float16* __restrict__ o0,
                                              _Float16* __restrict__ o1,
                                              _Float16* __restrict__ o2,
                                              _Float16* __restrict__ o3) {
  __shared__ float tile[64][65];
  const float* w = (blockIdx.z == 0) ? w0 : (blockIdx.z == 1) ? w1 : (blockIdx.z == 2) ? w2 : w3;
  _Float16* wt = (blockIdx.z == 0) ? o0 : (blockIdx.z == 1) ? o1 : (blockIdx.z == 2) ? o2 : o3;
  int k0 = blockIdx.y * 64, n0 = blockIdx.x * 64;
  int t = threadIdx.x;
  int r = t >> 2, c0 = (t & 3) * 16;
  const float* ip = w + (size_t)(k0 + r) * D_ + n0 + c0;
#pragma unroll
  for (int j = 0; j < 16; j += 4) {
    f32x4 v = *(const f32x4*)(ip + j);
    tile[r][c0 + j] = v[0]; tile[r][c0 + j + 1] = v[1];
    tile[r][c0 + j + 2] = v[2]; tile[r][c0 + j + 3] = v[3];
  }
  __syncthreads();
  _Float16* op = wt + (size_t)(n0 + r) * D_ + k0 + c0;
#pragma unroll
  for (int j = 0; j < 16; j += 8) {
    fp16x8 v;
#pragma unroll
    for (int q = 0; q < 8; ++q) v[q] = (_Float16)tile[c0 + j + q][r];
    *(fp16x8*)(op + j) = v;
  }
}

// ---------------- 256x128-tile counted-vmcnt GEMM (8 waves, 4M x 2N) ----------------
// C[M][*] = A16[M][2048] * (BT16[*][2048])^T
// MODE 0: QKV fused (N=6144): n<2048 -> rope->Qo; n<4096 -> rope->Ko; else Vo blocked.
// MODE 1: plain fp32 store (N=2048) to Cf.
// LDS 96KB: A [2buf][4u][64][64] halfs @0, B [2buf][2u][64][64] @32768.
// XOR swizzle via pre-swizzled global source (slot lc^lr), reads XOR (row&7)*8 halfs.
// Schedule per K-tile: issue 6 gloads for t+1 -> vmcnt(6) -> barrier -> 16 ds_read
// + 32 MFMA (compiler-scheduled, setprio-wrapped) -> barrier. Never drains mid-loop.
// Session-best configuration (rd8: QKV 130us, total 222.3); rounds 9-12 schedule
// variants (depth-2, 2-phase, 256x256, 4-phase) all null or regression -> plateau.
template <int MODE>
__global__ __launch_bounds__(512) void k_gemm256(const _Float16* __restrict__ A,
                                                 const _Float16* __restrict__ BT,
                                                 const float* __restrict__ cosT,
                                                 const float* __restrict__ sinT,
                                                 _Float16* __restrict__ Qo,
                                                 _Float16* __restrict__ Ko,
                                                 _Float16* __restrict__ Vo,
                                                 float* __restrict__ Cf) {
  __shared__ __align__(16) _Float16 smem[49152];  // 96 KiB
  const int tid = threadIdx.x;
  const int w = tid >> 6, lane = tid & 63;
  const int l15 = lane & 15, lg = lane >> 4;
  // bijective XCD mapping: XCD x owns NPX n-tiles x all 16 m-tiles
  const int NPX = (MODE == 0) ? 6 : 2;  // n-tiles per XCD (48 or 16 total)
  const int bid = blockIdx.x;
  const int xcd = bid & 7, j = bid >> 3;
  const int m0 = (j / NPX) * 256;
  const int n0 = (xcd * NPX + j % NPX) * 128;
  const int wm = (w >> 1) * 64;  // wave M-base within tile
  const int wn = (w & 1) * 64;   // wave N-base within tile
  // staging coords: wave w covers rows [w*8, w*8+8) of each 64-row unit; slot lc
  const int lr = lane >> 3, lc = lane & 7;
  const int scol = (lc ^ lr) << 3;  // pre-swizzled source col (halfs)
  const _Float16* Asrc = A + (size_t)(m0 + w * 8 + lr) * 2048 + scol;
  const _Float16* Bsrc = BT + (size_t)(n0 + w * 8 + lr) * 2048 + scol;
  _Float16* dstA = smem + w * 512;
  _Float16* dstB = smem + 32768 + w * 512;

  auto stageA = [&](int stg, int u, int k0) {
    gl_lds16(Asrc + (size_t)u * 64 * 2048 + k0, dstA + stg * 16384 + u * 4096);
  };
  auto stageB = [&](int stg, int u, int k0) {
    gl_lds16(Bsrc + (size_t)u * 64 * 2048 + k0, dstB + stg * 8192 + u * 4096);
  };

  f32x4 acc[4][4] = {};

  // prologue: tile 0 -> buf 0 (wait happens inside first loop iteration)
#pragma unroll
  for (int u = 0; u < 4; ++u) stageA(0, u, 0);
  stageB(0, 0, 0); stageB(0, 1, 0);

  for (int t = 0; t < 32; ++t) {
    const int cur = t & 1, stg = cur ^ 1;
    if (t + 1 < 32) {
      const int k1 = (t + 1) * 64;
#pragma unroll
      for (int u = 0; u < 4; ++u) stageA(stg, u, k1);
      stageB(stg, 0, k1); stageB(stg, 1, k1);
      asm volatile("s_waitcnt vmcnt(6)" ::: "memory");  // tile t arrived; t+1 in flight
    } else {
      asm volatile("s_waitcnt vmcnt(0)" ::: "memory");
    }
    __builtin_amdgcn_s_barrier();

    fp16x8 af[4][2], bf[4][2];
#pragma unroll
    for (int mi = 0; mi < 4; ++mi)
#pragma unroll
      for (int ks = 0; ks < 2; ++ks) {
        const int row = wm + mi * 16 + l15;  // [0,256)
        af[mi][ks] = *(const fp16x8*)(smem + cur * 16384 + (row >> 6) * 4096 +
                                      (row & 63) * 64 + ((ks * 32 + lg * 8) ^ ((l15 & 7) * 8)));
      }
#pragma unroll
    for (int ni = 0; ni < 4; ++ni)
#pragma unroll
      for (int ks = 0; ks < 2; ++ks) {
        const int row = wn + ni * 16 + l15;  // [0,128)
        bf[ni][ks] = *(const fp16x8*)(smem + 32768 + cur * 8192 + (row >> 6) * 4096 +
                                      (row & 63) * 64 + ((ks * 32 + lg * 8) ^ ((l15 & 7) * 8)));
      }
    __builtin_amdgcn_s_setprio(1);
#pragma unroll
    for (int mi = 0; mi < 4; ++mi)
#pragma unroll
      for (int ni = 0; ni < 4; ++ni)
#pragma unroll
        for (int ks = 0; ks < 2; ++ks)
          acc[mi][ni] = __builtin_amdgcn_mfma_f32_16x16x32_f16(af[mi][ks], bf[ni][ks],
                                                               acc[mi][ni], 0, 0, 0);
    __builtin_amdgcn_s_setprio(0);
    __builtin_amdgcn_s_barrier();  // all waves done reading buf[cur] before t+2 overwrites
  }

  if (MODE == 0) {
    const int region = n0 >> 11;  // 0=Q, 1=K, 2=V (128-tile never crosses regions)
    if (region < 2) {
      _Float16* Out = (region == 0) ? Qo : Ko;
#pragma unroll
      for (int mi = 0; mi < 4; ++mi)
#pragma unroll
        for (int ni = 0; ni < 4; ++ni) {
          const int col = n0 + wn + 16 * ni + l15;
          const int d = col & 127;
          const int h = (col >> 7) & 15;
          const int dp = d >> 1;
          const bool odd = d & 1;
#pragma unroll
          for (int i = 0; i < 4; ++i) {
            const int row = m0 + wm + 16 * mi + 4 * lg + i;
            const int b = row >> 11, sl = row & 2047;
            const float self = acc[mi][ni][i];
            const float partner = __shfl_xor(self, 1);
            const float c = cosT[sl * 64 + dp], sn = sinT[sl * 64 + dp];
            const float val = odd ? (partner * sn + self * c) : (self * c - partner * sn);
            Out[(((size_t)b * H_ + h) * S_ + sl) * HD_ + d] = (_Float16)val;
          }
        }
    } else {
#pragma unroll
      for (int mi = 0; mi < 4; ++mi)
#pragma unroll
        for (int ni = 0; ni < 4; ++ni) {
          const int col = n0 + wn + 16 * ni + l15;
          const int d = col & 127;
          const int h = (col >> 7) & 15;
          const int row0 = m0 + wm + 16 * mi + 4 * lg;
          const int b = row0 >> 11, sl0 = row0 & 2047;
          const int kb = sl0 >> 4, kin = sl0 & 15;
          fp16x4 v4;
#pragma unroll
          for (int i = 0; i < 4; ++i) v4[i] = (_Float16)acc[mi][ni][i];
          *(fp16x4*)(Vo + ((((size_t)b * H_ + h) * 128 + kb) * 128 + d) * 16 + kin) = v4;
        }
    }
  } else {
#pragma unroll
    for (int mi = 0; mi < 4; ++mi)
#pragma unroll
      for (int ni = 0; ni < 4; ++ni) {
        const size_t row = m0 + wm + 16 * mi + 4 * lg;
        const size_t col = n0 + wn + 16 * ni + l15;
#pragma unroll
        for (int i = 0; i < 4; ++i)
          Cf[(row + i) * 2048 + col] = acc[mi][ni][i];
      }
  }
}

// ---------------- block-sparse flash attention, paired q-groups ----------------
// WG p handles q-groups qgA=31-p then qgB=p (flat chunk list, prefetch spans the
// boundary). Wave w owns qb=4*qg+w. K/V staged via global_load_lds, double-buffered.
__global__ __launch_bounds__(256) void k_attn(const _Float16* __restrict__ Q,
                                              const _Float16* __restrict__ K,
                                              const _Float16* __restrict__ Vb,
                                              _Float16* __restrict__ Oa) {
  __shared__ __align__(16) _Float16 sK[2][2][2048];  // [buf][slot][16k x 128d swizzled]
  __shared__ __align__(16) _Float16 sV[2][2][2048];  // [buf][slot][128d x 16k]
  const int p = blockIdx.x;
  const int qgA = 31 - p, qgB = p;
  const int hh = blockIdx.y, b = blockIdx.z;
  const int t = threadIdx.x;
  const int w = t >> 6, lane = t & 63;
  const int l15 = lane & 15, lg = lane >> 4, g4 = lg * 4;
  const size_t bh = (size_t)b * H_ + hh;
  const float scale = 0.08838834764831845f;  // 1/sqrt(128)

  const int qbA = 4 * qgA + w, qbB = 4 * qgB + w;
  const int LA = qgA + 4, LB = qgB + 4;
  const int nchA = (LA + 1) >> 1, nchB = (LB + 1) >> 1;
  const int total = nchA + nchB;

  // Q fragments for both groups (16x16x32 B-operand: 8 contiguous d per lane)
  const _Float16* QpA = Q + (bh * S_ + (size_t)qbA * 16 + l15) * HD_ + lg * 8;
  const _Float16* QpB = Q + (bh * S_ + (size_t)qbB * 16 + l15) * HD_ + lg * 8;
  fp16x8 qfA[4], qfB[4];
#pragma unroll
  for (int dd = 0; dd < 4; ++dd) {
    qfA[dd] = *(const fp16x8*)(QpA + dd * 32);
    qfB[dd] = *(const fp16x8*)(QpB + dd * 32);
  }
  f32x4 o[8] = {};
  float mrun = -3.0e38f, lsum = 0.f;

  // staging source coords (K pre-swizzled so LDS-linear dest ^ read-swizzle match)
  const int sr = t >> 4, sc = t & 15;
  const int ksrc_off = sr * 128 + (sc ^ (sr & 7)) * 8;  // halfs
  const _Float16* Kb_g = K + bh * S_ * HD_;
  const _Float16* Vb_g = Vb + bh * (size_t)(128 * 2048);

  auto kbof = [&](int qg, int idx) { return idx < qg ? 4 * idx + 3 : 3 * qg + idx; };
  auto chunk_kbs = [&](int ci, int& kb0, int& kb1) {
    int qg, cil;
    if (ci < nchA) { qg = qgA; cil = ci; } else { qg = qgB; cil = ci - nchA; }
    const int L = qg + 4;
    const int i0 = 2 * cil, i1 = i0 + 1;
    kb0 = kbof(qg, i0);
    kb1 = (i1 < L) ? kbof(qg, i1) : kb0;
  };
  auto stage = [&](int buf, int ci) {
    int kb0, kb1;
    chunk_kbs(ci, kb0, kb1);
    gl_lds16(Kb_g + (size_t)kb0 * 2048 + ksrc_off, &sK[buf][0][w * 512]);
    gl_lds16(Kb_g + (size_t)kb1 * 2048 + ksrc_off, &sK[buf][1][w * 512]);
    gl_lds16(Vb_g + (size_t)kb0 * 2048 + t * 8, &sV[buf][0][w * 512]);
    gl_lds16(Vb_g + (size_t)kb1 * 2048 + t * 8, &sV[buf][1][w * 512]);
  };
  auto flush = [&](int qb) {
    const float inv = 1.f / lsum;
    f32x4 li;
#pragma unroll
    for (int i = 0; i < 4; ++i) li[i] = __shfl(inv, g4 + i);
    _Float16* Op = Oa + ((size_t)b * S_ + (size_t)qb * 16 + g4) * D_ + (size_t)hh * HD_ + l15;
#pragma unroll
    for (int ni = 0; ni < 8; ++ni)
#pragma unroll
      for (int i = 0; i < 4; ++i)
        Op[(size_t)i * D_ + 16 * ni] = (_Float16)(o[ni][i] * li[i]);
  };

  stage(0, 0);

  for (int ci = 0; ci < total; ++ci) {
    const int cur = ci & 1;
    if (ci == nchA) {  // group A complete: write it out, reset state for B
      flush(qbA);
#pragma unroll
      for (int ni = 0; ni < 8; ++ni) o[ni] = f32x4{0.f, 0.f, 0.f, 0.f};
      mrun = -3.0e38f;
      lsum = 0.f;
    }
    if (ci + 1 < total) {
      stage(cur ^ 1, ci + 1);
      asm volatile("s_waitcnt vmcnt(4)" ::: "memory");  // cur chunk arrived, next in flight
    } else {
      asm volatile("s_waitcnt vmcnt(0)" ::: "memory");
    }
    __builtin_amdgcn_s_barrier();

    const bool inA = ci < nchA;
    const int qg = inA ? qgA : qgB;
    const int qb = inA ? qbA : qbB;
    const int cil = inA ? ci : ci - nchA;
    const int L = qg + 4;
    int kb0, kb1;
    chunk_kbs(ci, kb0, kb1);
    const bool v0 = kb0 <= qb;
    const bool v1 = (2 * cil + 1 < L) && (kb1 <= qb);
    f32x4 st[2];
    const float in0 = v0 ? 0.f : -1.0e30f, in1 = v1 ? 0.f : -1.0e30f;
    st[0] = f32x4{in0, in0, in0, in0};
    st[1] = f32x4{in1, in1, in1, in1};

    // QK^T via 16x16x32: A=K (16 keys x 32 d), B=Q (16 qrows x 32 d)
    const char* kl = (const char*)&sK[cur][0][0];
    const int krow = l15 * 256;
#pragma unroll
    for (int dd = 0; dd < 4; ++dd) {
      const int co = ((dd * 4 + lg) ^ (l15 & 7)) * 16;
      fp16x8 k0 = *(const fp16x8*)(kl + krow + co);
      fp16x8 k1 = *(const fp16x8*)(kl + 4096 + krow + co);
      const fp16x8 qf = inA ? qfA[dd] : qfB[dd];
      st[0] = __builtin_amdgcn_mfma_f32_16x16x32_f16(k0, qf, st[0], 0, 0, 0);
      st[1] = __builtin_amdgcn_mfma_f32_16x16x32_f16(k1, qf, st[1], 0, 0, 0);
    }
    // softmax over the 32 keys
    float bm = -3.0e38f;
#pragma unroll
    for (int j = 0; j < 2; ++j)
#pragma unroll
      for (int i = 0; i < 4; ++i) {
        st[j][i] *= scale;
        bm = fmaxf(bm, st[j][i]);
      }
    bm = fmaxf(bm, __shfl_xor(bm, 16));
    bm = fmaxf(bm, __shfl_xor(bm, 32));
    const float mnew = fmaxf(mrun, bm);
    const float corr = __expf(mrun - mnew);
    float pr[2][4];
    float ps = 0.f;
#pragma unroll
    for (int j = 0; j < 2; ++j)
#pragma unroll
      for (int i = 0; i < 4; ++i) {
        pr[j][i] = __expf(st[j][i] - mnew);
        ps += pr[j][i];
      }
    ps += __shfl_xor(ps, 16);
    ps += __shfl_xor(ps, 32);
    lsum = lsum * corr + ps;
    mrun = mnew;
    f32x4 c4;
#pragma unroll
    for (int i = 0; i < 4; ++i) c4[i] = __shfl(corr, g4 + i);
#pragma unroll
    for (int ni = 0; ni < 8; ++ni) {
      o[ni][0] *= c4[0]; o[ni][1] *= c4[1]; o[ni][2] *= c4[2]; o[ni][3] *= c4[3];
    }
    fp16x4 ph0 = {(_Float16)pr[0][0], (_Float16)pr[0][1], (_Float16)pr[0][2], (_Float16)pr[0][3]};
    fp16x4 ph1 = {(_Float16)pr[1][0], (_Float16)pr[1][1], (_Float16)pr[1][2], (_Float16)pr[1][3]};
    const char* vl = (const char*)&sV[cur][0][0];
#pragma unroll
    for (int ni = 0; ni < 8; ++ni) {
      const int vo = (16 * ni + l15) * 32 + g4 * 2;
      fp16x4 vv0 = *(const fp16x4*)(vl + vo);
      fp16x4 vv1 = *(const fp16x4*)(vl + 4096 + vo);
      o[ni] = __builtin_amdgcn_mfma_f32_16x16x16f16(ph0, vv0, o[ni], 0, 0, 0);
      o[ni] = __builtin_amdgcn_mfma_f32_16x16x16f16(ph1, vv1, o[ni], 0, 0, 0);
    }
    __builtin_amdgcn_s_barrier();  // all waves done reading buf before it's re-staged
  }

  flush(qbB);
}

extern "C" void kernel_launch(void* const* d_in, const int* in_sizes, int n_in,
                              void* d_out, int out_size, void* d_ws, size_t ws_size,
                              hipStream_t stream) {
  const float* x = (const float*)d_in[0];
  const float* cosT = (const float*)d_in[1];
  const float* sinT = (const float*)d_in[2];
  const float* wq = (const float*)d_in[3];
  const float* wk = (const float*)d_in[4];
  const float* wv = (const float*)d_in[5];
  const float* wo = (const float*)d_in[6];
  float* out = (float*)d_out;
  char* ws = (char*)d_ws;

  _Float16* x16 = (_Float16*)(ws);                    // 16MB, reused as attn out
  _Float16* wtq = (_Float16*)(ws + (16ull << 20));    // 8MB each; wtq/wtk/wtv contiguous = BT[6144][2048]
  _Float16* wtk = (_Float16*)(ws + (24ull << 20));
  _Float16* wtv = (_Float16*)(ws + (32ull << 20));
  _Float16* wto = (_Float16*)(ws + (40ull << 20));
  _Float16* Q16 = (_Float16*)(ws + (48ull << 20));    // 16MB
  _Float16* K16 = (_Float16*)(ws + (64ull << 20));    // 16MB
  _Float16* Vb16 = (_Float16*)(ws + (80ull << 20));   // 16MB (blocked V)

  k_cast<<<8192, 256, 0, stream>>>(x, x16, (B_ * S_ * D_) / 4);
  k_trw4<<<dim3(32, 32, 4), 256, 0, stream>>>(wq, wk, wv, wo, wtq, wtk, wtv, wto);

  k_gemm256<0><<<768, 512, 0, stream>>>(x16, wtq, cosT, sinT, Q16, K16, Vb16, nullptr);

  _Float16* attn16 = x16;  // x16 no longer needed after QKV GEMM
  k_attn<<<dim3(16, H_, B_), 256, 0, stream>>>(Q16, K16, Vb16, attn16);

  k_gemm256<1><<<256, 512, 0, stream>>>(attn16, wto, nullptr, nullptr, nullptr, nullptr,
                                        nullptr, out);
}